// Round 4
// baseline (605.441 us; speedup 1.0000x reference)
//
#include <hip/hip_runtime.h>
#include <stdint.h>

#define M_DIM 8192
#define N_DIM 4096
#define K_DIM 4096
#define NKT   (K_DIM / 64)

typedef __attribute__((ext_vector_type(4)))  float  floatx4;
typedef __attribute__((ext_vector_type(8)))  _Float16 halfx8;

// ---------------------------------------------------------------------------
// FULLY FUSED dequant-GEMM. No cvt kernels, no f16 workspace.
// 256x256 tile, BK=64, 512 threads (8 waves 2x4), 16x16x32 f16 MFMA,
// 4-phase-per-K-tile counted-wait pipeline (structure proven r2: 1133 TF,
// 0 bank conflicts). Staging is now reg-staged: fp32 global -> cvt in regs
// (identical RTE numerics to the old cvt kernels) -> swizzled ds_write.
// Per-phase: issue one half-tile's 4x dwordx4 (fp32), write the half-tile
// loaded last phase (compiler emits counted vmcnt for the reg dataflow),
// 12/4/8/0 frag ds_reads, 16 MFMA (setprio), lgkmcnt(0), raw s_barrier.
// Loads are 1 phase (~600 cyc) ahead of use; ~95% of fp32 reads are L2/L3
// hits (each element re-read 16-32x), covered by that distance.
//
// LDS [2 buf][256 rows][64 halves] per matrix = 128 KiB. Chunk c (8 halves)
// of row r lives at slot c^(r&7) (both-sides swizzle: writer computes the
// same XOR the frag reader uses; wave ds_write banks uniform: bank depends
// only on slot, 8 lanes/slot).
//
// XCD swizzle (corrected after r3's FETCH regression): XCD x owns m-band
// [4x,4x+4) x all n, n 0..7 first then 8..15. Resident set round 1:
// A fp32 128 MB + W(n0-7) 32 MB = 160 MB < 256 MB L3; concurrent blocks on
// one XCD share A panels (8 readers) and W panels (4 readers) via L2.
// ---------------------------------------------------------------------------

#define LGKM0() asm volatile("s_waitcnt lgkmcnt(0)" ::: "memory")
#define BAR()   asm volatile("s_barrier" ::: "memory")

__device__ __forceinline__ void ld4(floatx4 r[4], const float* p) {
#pragma unroll
    for (int i = 0; i < 4; ++i) r[i] = ((const floatx4*)p)[i];
}

__device__ __forceinline__ void wrA(_Float16* p0, _Float16* p1, const floatx4 r[4]) {
    union { _Float16 h[8]; halfx8 v; } u0, u1;
#pragma unroll
    for (int j = 0; j < 4; ++j) {
        u0.h[j] = (_Float16)r[0][j]; u0.h[4 + j] = (_Float16)r[1][j];
        u1.h[j] = (_Float16)r[2][j]; u1.h[4 + j] = (_Float16)r[3][j];
    }
    *(halfx8*)p0 = u0.v;
    *(halfx8*)p1 = u1.v;
}

__device__ __forceinline__ void wrB(_Float16* p0, _Float16* p1, const floatx4 r[4],
                                    float s) {
    union { _Float16 h[8]; halfx8 v; } u0, u1;
#pragma unroll
    for (int j = 0; j < 4; ++j) {
        u0.h[j] = (_Float16)(r[0][j] * s); u0.h[4 + j] = (_Float16)(r[1][j] * s);
        u1.h[j] = (_Float16)(r[2][j] * s); u1.h[4 + j] = (_Float16)(r[3][j] * s);
    }
    *(halfx8*)p0 = u0.v;
    *(halfx8*)p1 = u1.v;
}

__device__ __forceinline__ void load_a(halfx8 af[4][2], const _Float16* sA, int bo,
                                       int ih, int wr, int l15, int sl0, int sl1) {
#pragma unroll
    for (int il = 0; il < 4; ++il) {
        const int ro = bo + (ih * 128 + il * 32 + wr * 16 + l15) * 64;
        af[il][0] = *(const halfx8*)&sA[ro + sl0];
        af[il][1] = *(const halfx8*)&sA[ro + sl1];
    }
}

__device__ __forceinline__ void load_b(halfx8 bf[2][2], const _Float16* sB, int bo,
                                       int jh, int wc, int l15, int sl0, int sl1) {
#pragma unroll
    for (int jl = 0; jl < 2; ++jl) {
        const int ro = bo + (jh * 128 + jl * 64 + wc * 16 + l15) * 64;
        bf[jl][0] = *(const halfx8*)&sB[ro + sl0];
        bf[jl][1] = *(const halfx8*)&sB[ro + sl1];
    }
}

__device__ __forceinline__ void mfma_q(floatx4 acc[8][4], int ih, int jh,
                                       const halfx8 af[4][2], const halfx8 bf[2][2]) {
    __builtin_amdgcn_s_setprio(1);
#pragma unroll
    for (int il = 0; il < 4; ++il)
#pragma unroll
    for (int jl = 0; jl < 2; ++jl)
#pragma unroll
    for (int ks = 0; ks < 2; ++ks)
        acc[ih * 4 + il][jh * 2 + jl] = __builtin_amdgcn_mfma_f32_16x16x32_f16(
            af[il][ks], bf[jl][ks], acc[ih * 4 + il][jh * 2 + jl], 0, 0, 0);
    __builtin_amdgcn_s_setprio(0);
}

__global__ __launch_bounds__(512, 2) void gemm_fused(const float* __restrict__ A32,
                                                     const float* __restrict__ W32,
                                                     const float* __restrict__ scales,
                                                     const float* __restrict__ bias,
                                                     float* __restrict__ C) {
    extern __shared__ _Float16 lds[];
    _Float16* sA = lds;                 // [2][256][64]
    _Float16* sB = lds + 2 * 256 * 64;  // [2][256][64]

    const int tid  = threadIdx.x;
    const int wid  = tid >> 6;
    const int lane = tid & 63;
    const int wr   = wid >> 2;          // 0..1
    const int wc   = wid & 3;           // 0..3
    const int l15  = lane & 15;
    const int lk   = lane >> 4;         // 0..3

    // XCD swizzle: xcd = lid%8 owns m-panels 4x..4x+3 for all 16 n-panels;
    // n 0..7 in its first 32 blocks, 8..15 in the second.  Bijective.
    const int lid = blockIdx.x;                 // 0..511
    const int xcd = lid & 7;
    const int jb  = lid >> 3;                   // 0..63
    const int n0  = ((jb & 7) + 8 * (jb >> 5)) * 256;
    const int m0  = (xcd * 4 + ((jb >> 3) & 3)) * 256;

    // Staging geometry: thread covers row (half)*128 + (tid>>2),
    // 16 consecutive floats at col (tid&3)*16, i.e. chunks c0, c0+1.
    const int srow = tid >> 2;                  // 0..127
    const int scol = (tid & 3) << 4;
    const float* Ag = A32 + (size_t)(m0 + srow) * K_DIM + scol;
    const float* Bg = W32 + (size_t)(n0 + srow) * K_DIM + scol;
    const size_t H1 = (size_t)128 * K_DIM;      // half1 row offset (fp32 elems)
    const int r7  = srow & 7;                   // (h*128)&7 == 0
    const int c0  = (tid & 3) << 1;
    const int wb  = srow * 64;                  // row base (elems) within half0
    const int ws0 = ((c0 ^ r7) << 3);
    const int ws1 = (((c0 + 1) ^ r7) << 3);
    // half1 region adds 8192 elems; buf1 adds 16384.

    // Fragment read: chunk ks*4+lk of row r at slot (ks*4+lk)^(r&7); frag
    // rows ≡ lane&7 (mod 8) since 16/32/64/128 are all multiples of 8.
    const int sl0 = (lk ^ (lane & 7)) * 8;
    const int sl1 = sl0 ^ 32;

    floatx4 acc[8][4] = {};
    halfx8 af[4][2], bf0[2][2], bf1[2][2];
    floatx4 rA0[4], rB0[4], rB1[4], rA1[4];
    float sB0v, sB1v;

    // Prologue: tile 0.  Load A0,B0 (+ issue B1 to keep queue warm), write
    // A0,B0 into buf0.  Compiler inserts counted vmcnt before reg reads.
    ld4(rA0, Ag);
    ld4(rB0, Bg);
    sB0v = scales[n0 + srow];                   // group 0, B0 row
    ld4(rB1, Bg + H1);
    sB1v = scales[n0 + 128 + srow];             // group 0, B1 row
    wrA(&sA[wb + ws0], &sA[wb + ws1], rA0);
    wrB(&sB[wb + ws0], &sB[wb + ws1], rB0, sB0v);
    LGKM0();

#pragma unroll 1
    for (int kt = 0; kt < NKT - 1; ++kt) {
        const int bo  = (kt & 1) * 16384;
        const int nbo = bo ^ 16384;
        const int kc0 = kt * 64;                // current tile k-col
        const int kc1 = kc0 + 64;               // next tile k-col
        const int g1  = ((kt + 1) >> 1) * N_DIM;
        // P1: compute q00 from A0,B0(kt); load A1(kt); write B1(kt).
        BAR();
        ld4(rA1, Ag + H1 + kc1 - 64);           // A1 of tile kt  (== +kc0)
        wrB(&sB[bo + 8192 + wb + ws0], &sB[bo + 8192 + wb + ws1], rB1, sB1v);
        load_a(af, sA, bo, 0, wr, l15, sl0, sl1);
        load_b(bf0, sB, bo, 0, wc, l15, sl0, sl1);
        mfma_q(acc, 0, 0, af, bf0);
        LGKM0();
        // P2: q01; load A0(kt+1); write A1(kt).
        BAR();
        ld4(rA0, Ag + kc1);
        wrA(&sA[bo + 8192 + wb + ws0], &sA[bo + 8192 + wb + ws1], rA1);
        load_b(bf1, sB, bo, 1, wc, l15, sl0, sl1);
        mfma_q(acc, 0, 1, af, bf1);
        LGKM0();
        // P3: q11; load B0(kt+1)+scale; write A0(kt+1) -> other buf.
        BAR();
        ld4(rB0, Bg + kc1);
        sB0v = scales[g1 + n0 + srow];
        wrA(&sA[nbo + wb + ws0], &sA[nbo + wb + ws1], rA0);
        load_a(af, sA, bo, 1, wr, l15, sl0, sl1);
        mfma_q(acc, 1, 1, af, bf1);
        LGKM0();
        // P4: q10; load B1(kt+1)+scale; write B0(kt+1) -> other buf.
        BAR();
        ld4(rB1, Bg + H1 + kc1);
        sB1v = scales[g1 + n0 + 128 + srow];
        wrB(&sB[nbo + wb + ws0], &sB[nbo + wb + ws1], rB0, sB0v);
        mfma_q(acc, 1, 0, af, bf0);
        LGKM0();
    }

    // Epilogue tile NKT-1 (odd -> buf1): nothing further to prefetch.
    {
        const int bo = ((NKT - 1) & 1) * 16384;
        const int kc = (NKT - 1) * 64;
        BAR();
        ld4(rA1, Ag + H1 + kc);                 // A1 of last tile
        wrB(&sB[bo + 8192 + wb + ws0], &sB[bo + 8192 + wb + ws1], rB1, sB1v);
        load_a(af, sA, bo, 0, wr, l15, sl0, sl1);
        load_b(bf0, sB, bo, 0, wc, l15, sl0, sl1);
        mfma_q(acc, 0, 0, af, bf0);
        LGKM0();
        BAR();
        wrA(&sA[bo + 8192 + wb + ws0], &sA[bo + 8192 + wb + ws1], rA1);
        load_b(bf1, sB, bo, 1, wc, l15, sl0, sl1);
        mfma_q(acc, 0, 1, af, bf1);
        LGKM0();
        BAR();
        load_a(af, sA, bo, 1, wr, l15, sl0, sl1);
        mfma_q(acc, 1, 1, af, bf1);
        mfma_q(acc, 1, 0, af, bf0);
    }

    // C epilogue: 16x16 C/D layout col = lane&15, row = (lane>>4)*4 + reg.
#pragma unroll
    for (int jh = 0; jh < 2; ++jh)
#pragma unroll
    for (int jl = 0; jl < 2; ++jl) {
        const int n = n0 + jh * 128 + jl * 64 + wc * 16 + l15;
        const float bv = bias[n];
#pragma unroll
        for (int ih = 0; ih < 2; ++ih)
#pragma unroll
        for (int il = 0; il < 4; ++il) {
            const int mb = m0 + ih * 128 + il * 32 + wr * 16 + lk * 4;
            const floatx4 v = acc[ih * 4 + il][jh * 2 + jl];
#pragma unroll
            for (int r = 0; r < 4; ++r)
                C[(size_t)(mb + r) * N_DIM + n] = v[r] + bv;
        }
    }
}

// ---------------------------------------------------------------------------

extern "C" void kernel_launch(void* const* d_in, const int* in_sizes, int n_in,
                              void* d_out, int out_size, void* d_ws, size_t ws_size,
                              hipStream_t stream) {
    const float* input   = (const float*)d_in[0];
    const float* qweight = (const float*)d_in[1];
    const float* scales  = (const float*)d_in[2];
    const float* bias    = (const float*)d_in[3];
    float* out = (float*)d_out;

    static bool attr_done = false;
    if (!attr_done) {
        (void)hipFuncSetAttribute((const void*)gemm_fused,
                                  hipFuncAttributeMaxDynamicSharedMemorySize,
                                  131072);
        attr_done = true;
    }
    gemm_fused<<<dim3(512), 512, 131072, stream>>>(input, qweight, scales, bias, out);
}

// Round 5
// 501.746 us; speedup vs baseline: 1.2067x; 1.2067x over previous
//
#include <hip/hip_runtime.h>
#include <stdint.h>

#define M_DIM 8192
#define N_DIM 4096
#define K_DIM 4096
#define NKT   (K_DIM / 64)

typedef __attribute__((ext_vector_type(4)))  float  floatx4;
typedef __attribute__((ext_vector_type(2)))  unsigned int uintx2;
typedef __attribute__((ext_vector_type(8)))  _Float16 halfx8;

// ---------------------------------------------------------------------------
// Conversion kernels (reverted to r2/r3 split form — ~55-65 us total, near
// their 48 us streaming roofline; r4 proved the residual was fixed harness
// overhead, not cvt). Coalesced float4 loads, 8B f16 stores, grid-stride.
// ---------------------------------------------------------------------------

#define A_F4 (M_DIM * K_DIM / 4)
#define W_F4 (N_DIM * K_DIM / 4)
#define CVT_BLOCKS 2048

__global__ __launch_bounds__(256) void cvt_a(const float* __restrict__ a_in,
                                             _Float16* __restrict__ a16) {
    const floatx4* a4 = (const floatx4*)a_in;
    uintx2* o2 = (uintx2*)a16;
    const int stride = CVT_BLOCKS * 256;
#pragma unroll 4
    for (int f = blockIdx.x * 256 + threadIdx.x; f < A_F4; f += stride) {
        floatx4 x = a4[f];
        union { _Float16 h[4]; uintx2 u; } p;
        p.h[0] = (_Float16)x[0]; p.h[1] = (_Float16)x[1];
        p.h[2] = (_Float16)x[2]; p.h[3] = (_Float16)x[3];
        o2[f] = p.u;
    }
}

__global__ __launch_bounds__(256) void cvt_w(const float* __restrict__ w_in,
                                             const float* __restrict__ scales,
                                             _Float16* __restrict__ w16) {
    const floatx4* w4 = (const floatx4*)w_in;
    uintx2* o2 = (uintx2*)w16;
    const int stride = CVT_BLOCKS * 256;
#pragma unroll 4
    for (int f = blockIdx.x * 256 + threadIdx.x; f < W_F4; f += stride) {
        const int o = f >> 10;
        const int grp = (f & 1023) >> 5;
        const float s = scales[grp * N_DIM + o];
        floatx4 x = w4[f];
        union { _Float16 h[4]; uintx2 u; } p;
        p.h[0] = (_Float16)(x[0] * s); p.h[1] = (_Float16)(x[1] * s);
        p.h[2] = (_Float16)(x[2] * s); p.h[3] = (_Float16)(x[3] * s);
        o2[f] = p.u;
    }
}

// ---------------------------------------------------------------------------
// 256x256 GEMM, BK=64, 512 threads (8 waves 2x4), 16x16x32 f16 MFMA.
// THIS ROUND: exact m201 phase microstructure replacing r2's one-barrier /
// three-vmcnt schedule:
//   phase p: { frag ds_reads; stage 1 half-tile (2 gld_lds); [lgkmcnt(8)];
//              BAR; lgkmcnt(0); setprio(1); 16 MFMA; setprio(0); BAR; }
//   vmcnt(6) ONCE per K-tile (at P4), prefetch stream 3 half-tiles ahead:
//   during tile t issue A1(t+1)@P1, A0(t+2)@P2, B0(t+2)@P3, B1(t+2)@P4.
// Region-reuse legality: each buf[t] region's last frag-read is in phase p,
// and every wave's lgkmcnt(0) precedes its second barrier of phase p, so by
// phase p+1 the region is free for tile t+2 staging.
// vmcnt ledger (per wave, 2 loads/half): at P4(t) outstanding = 7 halves;
// vmcnt(6) retires the 8 oldest loads = exactly tile t+1's 4 halves. The
// only drain-to-0 is at P4(NKT-2). Hand-verified.
// Fragment layout / XOR swizzle / epilogue identical to r2 (0 conflicts).
// ---------------------------------------------------------------------------

__device__ __forceinline__ void gld_lds16(const _Float16* g, _Float16* l) {
    __builtin_amdgcn_global_load_lds(
        (const __attribute__((address_space(1))) void*)g,
        (__attribute__((address_space(3))) void*)l, 16, 0, 0);
}

#define WAITV(n) asm volatile("s_waitcnt vmcnt(" #n ")" ::: "memory")
#define LGKM(n)  asm volatile("s_waitcnt lgkmcnt(" #n ")" ::: "memory")
#define BAR()    asm volatile("s_barrier" ::: "memory")

// Stage half-tile h (rows h*128..h*128+127) of tile `t` into buf[t&1].
__device__ __forceinline__ void issue_half(const _Float16* gbase, _Float16* sbase,
                                           int t, int h, int wid) {
    const int b = t & 1;
    const int kcol = t * 64;
#pragma unroll
    for (int q2 = 0; q2 < 2; ++q2) {
        const int q = 2 * h + q2;
        gld_lds16(gbase + (size_t)q * 64 * K_DIM + kcol,
                  sbase + b * 16384 + q * 4096 + wid * 512);
    }
}

__device__ __forceinline__ void load_a(halfx8 af[4][2], const _Float16* sA, int bo,
                                       int ih, int wr, int l15, int sl0, int sl1) {
#pragma unroll
    for (int il = 0; il < 4; ++il) {
        const int ro = bo + (ih * 128 + il * 32 + wr * 16 + l15) * 64;
        af[il][0] = *(const halfx8*)&sA[ro + sl0];
        af[il][1] = *(const halfx8*)&sA[ro + sl1];
    }
}

__device__ __forceinline__ void load_b(halfx8 bf[2][2], const _Float16* sB, int bo,
                                       int jh, int wc, int l15, int sl0, int sl1) {
#pragma unroll
    for (int jl = 0; jl < 2; ++jl) {
        const int ro = bo + (jh * 128 + jl * 64 + wc * 16 + l15) * 64;
        bf[jl][0] = *(const halfx8*)&sB[ro + sl0];
        bf[jl][1] = *(const halfx8*)&sB[ro + sl1];
    }
}

__device__ __forceinline__ void mfma_q(floatx4 acc[8][4], int ih, int jh,
                                       const halfx8 af[4][2], const halfx8 bf[2][2]) {
    __builtin_amdgcn_s_setprio(1);
#pragma unroll
    for (int il = 0; il < 4; ++il)
#pragma unroll
    for (int jl = 0; jl < 2; ++jl)
#pragma unroll
    for (int ks = 0; ks < 2; ++ks)
        acc[ih * 4 + il][jh * 2 + jl] = __builtin_amdgcn_mfma_f32_16x16x32_f16(
            af[il][ks], bf[jl][ks], acc[ih * 4 + il][jh * 2 + jl], 0, 0, 0);
    __builtin_amdgcn_s_setprio(0);
}

__global__ __launch_bounds__(512, 2) void gemm_f16(const _Float16* __restrict__ A,
                                                   const _Float16* __restrict__ B,
                                                   const float* __restrict__ bias,
                                                   float* __restrict__ C) {
    extern __shared__ _Float16 lds[];
    _Float16* sA = lds;                 // [2][256][64]
    _Float16* sB = lds + 2 * 256 * 64;  // [2][256][64]

    const int tid  = threadIdx.x;
    const int wid  = tid >> 6;
    const int lane = tid & 63;
    const int wr   = wid >> 2;          // 0..1
    const int wc   = wid & 3;           // 0..3
    const int l15  = lane & 15;
    const int lk   = lane >> 4;         // 0..3

    const int m0 = blockIdx.y * 256;
    const int n0 = blockIdx.x * 256;

    // Staging: thread covers row q*64 + (tid>>3); LDS slot tid&7 holds global
    // chunk (tid&7)^(row&7) (pre-swizzled source, linear gld_lds dest).
    const int rowt = tid >> 3;
    const int g8   = ((tid & 7) ^ ((tid >> 3) & 7)) * 8;
    const _Float16* Abase = A + (size_t)(m0 + rowt) * K_DIM + g8;
    const _Float16* Bbase = B + (size_t)(n0 + rowt) * K_DIM + g8;

    // Fragment read: chunk ks*4+lk of row r at slot (ks*4+lk)^(r&7).
    const int sl0 = (lk ^ (lane & 7)) * 8;
    const int sl1 = sl0 ^ 32;

    floatx4 acc[8][4] = {};
    halfx8 af[4][2], bf0[2][2], bf1[2][2];

    // Prologue: tile0's 4 halves; pace; tile1's first 3 halves; vouch tile0.
    issue_half(Abase, sA, 0, 0, wid);
    issue_half(Bbase, sB, 0, 0, wid);
    issue_half(Bbase, sB, 0, 1, wid);
    issue_half(Abase, sA, 0, 1, wid);
    WAITV(4);
    issue_half(Abase, sA, 1, 0, wid);
    issue_half(Bbase, sB, 1, 0, wid);
    issue_half(Bbase, sB, 1, 1, wid);
    WAITV(6);
    BAR();

#pragma unroll 1
    for (int t = 0; t < NKT - 2; ++t) {         // t = 0 .. NKT-3
        const int bo = (t & 1) * 16384;
        // P1: q00.  12 ds_reads; stage A1(t+1).
        load_a(af, sA, bo, 0, wr, l15, sl0, sl1);
        load_b(bf0, sB, bo, 0, wc, l15, sl0, sl1);
        issue_half(Abase, sA, t + 1, 1, wid);
        LGKM(8);
        BAR(); LGKM(0);
        mfma_q(acc, 0, 0, af, bf0);
        BAR();
        // P2: q01.  4 ds_reads; stage A0(t+2) (A0 region of buf[t] free).
        load_b(bf1, sB, bo, 1, wc, l15, sl0, sl1);
        issue_half(Abase, sA, t + 2, 0, wid);
        BAR(); LGKM(0);
        mfma_q(acc, 0, 1, af, bf1);
        BAR();
        // P3: q11.  8 ds_reads; stage B0(t+2).
        load_a(af, sA, bo, 1, wr, l15, sl0, sl1);
        issue_half(Bbase, sB, t + 2, 0, wid);
        BAR(); LGKM(0);
        mfma_q(acc, 1, 1, af, bf1);
        BAR();
        // P4: q10 (frags already in regs).  Stage B1(t+2); the ONE vmcnt:
        // retires the 8 oldest loads = all of tile t+1.
        issue_half(Bbase, sB, t + 2, 1, wid);
        WAITV(6);
        BAR();
        mfma_q(acc, 1, 0, af, bf0);
        BAR();
    }

    // Peeled tile NKT-2 (even -> buf0): only A1(NKT-1) left to stage.
    {
        const int bo = ((NKT - 2) & 1) * 16384;
        load_a(af, sA, bo, 0, wr, l15, sl0, sl1);
        load_b(bf0, sB, bo, 0, wc, l15, sl0, sl1);
        issue_half(Abase, sA, NKT - 1, 1, wid);
        LGKM(8);
        BAR(); LGKM(0);
        mfma_q(acc, 0, 0, af, bf0);
        BAR();
        load_b(bf1, sB, bo, 1, wc, l15, sl0, sl1);
        BAR(); LGKM(0);
        mfma_q(acc, 0, 1, af, bf1);
        BAR();
        load_a(af, sA, bo, 1, wr, l15, sl0, sl1);
        BAR(); LGKM(0);
        mfma_q(acc, 1, 1, af, bf1);
        BAR();
        WAITV(0);                              // the only full drain
        BAR();
        mfma_q(acc, 1, 0, af, bf0);
        BAR();
    }

    // Peeled tile NKT-1 (odd -> buf1): pure compute, compiler auto-waits.
    {
        const int bo = ((NKT - 1) & 1) * 16384;
        load_a(af, sA, bo, 0, wr, l15, sl0, sl1);
        load_b(bf0, sB, bo, 0, wc, l15, sl0, sl1);
        mfma_q(acc, 0, 0, af, bf0);
        load_b(bf1, sB, bo, 1, wc, l15, sl0, sl1);
        mfma_q(acc, 0, 1, af, bf1);
        load_a(af, sA, bo, 1, wr, l15, sl0, sl1);
        mfma_q(acc, 1, 1, af, bf1);
        mfma_q(acc, 1, 0, af, bf0);
    }

    // Epilogue: 16x16 C/D layout col = lane&15, row = (lane>>4)*4 + reg.
#pragma unroll
    for (int jh = 0; jh < 2; ++jh)
#pragma unroll
    for (int jl = 0; jl < 2; ++jl) {
        const int n = n0 + jh * 128 + jl * 64 + wc * 16 + l15;
        const float bv = bias[n];
#pragma unroll
        for (int ih = 0; ih < 2; ++ih)
#pragma unroll
        for (int il = 0; il < 4; ++il) {
            const int mb = m0 + ih * 128 + il * 32 + wr * 16 + lk * 4;
            const floatx4 v = acc[ih * 4 + il][jh * 2 + jl];
#pragma unroll
            for (int r = 0; r < 4; ++r)
                C[(size_t)(mb + r) * N_DIM + n] = v[r] + bv;
        }
    }
}

// ---------------------------------------------------------------------------
// Exact fp32 fallback (only if workspace is too small) — slow but correct.
// ---------------------------------------------------------------------------

__global__ __launch_bounds__(256) void fallback_gemm(const float* __restrict__ A,
                                                     const float* __restrict__ W,
                                                     const float* __restrict__ S,
                                                     const float* __restrict__ bias,
                                                     float* __restrict__ C) {
    const long idx = (long)blockIdx.x * 256 + threadIdx.x;
    const int m = (int)(idx >> 12);
    const int n = (int)(idx & 4095);
    const float* a = A + (size_t)m * K_DIM;
    const float* w = W + (size_t)n * K_DIM;
    float acc = 0.f;
    for (int g = 0; g < 32; ++g) {
        const float s = S[g * N_DIM + n];
        float part = 0.f;
        const int kb = g * 128;
#pragma unroll 4
        for (int k = kb; k < kb + 128; ++k) part += a[k] * w[k];
        acc += part * s;
    }
    C[idx] = acc + bias[n];
}

// ---------------------------------------------------------------------------

extern "C" void kernel_launch(void* const* d_in, const int* in_sizes, int n_in,
                              void* d_out, int out_size, void* d_ws, size_t ws_size,
                              hipStream_t stream) {
    const float* input   = (const float*)d_in[0];
    const float* qweight = (const float*)d_in[1];
    const float* scales  = (const float*)d_in[2];
    const float* bias    = (const float*)d_in[3];
    float* out = (float*)d_out;

    const size_t a_bytes = (size_t)M_DIM * K_DIM * sizeof(_Float16); // 64 MiB
    const size_t w_bytes = (size_t)N_DIM * K_DIM * sizeof(_Float16); // 32 MiB

    if (ws_size >= a_bytes + w_bytes) {
        _Float16* a16 = (_Float16*)d_ws;
        _Float16* w16 = (_Float16*)((char*)d_ws + a_bytes);

        cvt_a<<<CVT_BLOCKS, 256, 0, stream>>>(input, a16);
        cvt_w<<<CVT_BLOCKS, 256, 0, stream>>>(qweight, scales, w16);

        static bool attr_done = false;
        if (!attr_done) {
            (void)hipFuncSetAttribute((const void*)gemm_f16,
                                      hipFuncAttributeMaxDynamicSharedMemorySize,
                                      131072);
            attr_done = true;
        }
        gemm_f16<<<dim3(N_DIM / 256, M_DIM / 256), 512, 131072, stream>>>(
            a16, w16, bias, out);
    } else {
        fallback_gemm<<<((size_t)M_DIM * N_DIM) / 256, 256, 0, stream>>>(
            input, qweight, scales, bias, out);
    }
}